// Round 9
// baseline (436.123 us; speedup 1.0000x reference)
//
#include <hip/hip_runtime.h>
#include <hip/hip_bf16.h>
#include <math.h>

#define B_   4
#define C_   128
#define H_   96
#define W_   192
#define HW_  (H_*W_)

#define TH 4
#define TW 16
#define HX 18          // TW+2
#define HPX 108        // (TH+2)*HX
#define SHS 136        // sH row stride in shorts

typedef __attribute__((ext_vector_type(8))) short bf16x8;
typedef __attribute__((ext_vector_type(4))) float f32x4;

__device__ __forceinline__ unsigned short f2bf(float f) {
    __hip_bfloat16 h = __float2bfloat16(f);
    return *(unsigned short*)&h;
}
__device__ __forceinline__ float bflo(unsigned u) { return __uint_as_float(u << 16); }
__device__ __forceinline__ float bfhi(unsigned u) { return __uint_as_float(u & 0xFFFF0000u); }

// ---------------------------------------------------------------------------
// prep (identical to round 8)
// ---------------------------------------------------------------------------
__global__ __launch_bounds__(256) void prep_kernel(
    const float* __restrict__ Wq, const float* __restrict__ Wk,
    const float* __restrict__ bq, const float* __restrict__ bk,
    short* __restrict__ Apack, float* __restrict__ u2,
    float* __restrict__ v2, float* __restrict__ c0)
{
    if (blockIdx.x < 8) {
        const int rb   = blockIdx.x;
        const int t    = threadIdx.x;
        const int lane = t & 63;
        const int row  = rb * 16 + (lane & 15);
        const int colb = (t >> 6) * 32 + (lane >> 4) * 8;
        float a[8];
#pragma unroll
        for (int j = 0; j < 8; ++j) a[j] = 0.f;
#pragma unroll 2
        for (int c = 0; c < C_; c += 4) {
            float wk[4];
            float4 wv[4][2];
#pragma unroll
            for (int u = 0; u < 4; ++u) {
                wk[u] = Wk[(c + u) * C_ + row];
                wv[u][0] = *(const float4*)(Wq + (c + u) * C_ + colb);
                wv[u][1] = *(const float4*)(Wq + (c + u) * C_ + colb + 4);
            }
#pragma unroll
            for (int u = 0; u < 4; ++u) {
                a[0] = fmaf(wk[u], wv[u][0].x, a[0]); a[1] = fmaf(wk[u], wv[u][0].y, a[1]);
                a[2] = fmaf(wk[u], wv[u][0].z, a[2]); a[3] = fmaf(wk[u], wv[u][0].w, a[3]);
                a[4] = fmaf(wk[u], wv[u][1].x, a[4]); a[5] = fmaf(wk[u], wv[u][1].y, a[5]);
                a[6] = fmaf(wk[u], wv[u][1].z, a[6]); a[7] = fmaf(wk[u], wv[u][1].w, a[7]);
            }
        }
        bf16x8 v;
#pragma unroll
        for (int j = 0; j < 8; ++j) v[j] = (short)f2bf(a[j]);
        *(bf16x8*)(Apack + ((size_t)rb * 256 + t) * 8) = v;
    } else {
        const int t = threadIdx.x;
        if (t < 128) {
            float a = 0.f;
            for (int c = 0; c < C_; ++c) a = fmaf(Wk[c * C_ + t], bq[c], a);
            u2[t] = a;
        } else {
            const int i = t - 128;
            float a = 0.f;
            for (int c = 0; c < C_; ++c) a = fmaf(Wq[c * C_ + i], bk[c], a);
            v2[i] = a;
        }
        if (t == 0) {
            float a = 0.f;
            for (int c = 0; c < C_; ++c) a = fmaf(bq[c], bk[c], a);
            c0[0] = a;
        }
    }
}

// ---------------------------------------------------------------------------
// fused (identical to round 8)
// ---------------------------------------------------------------------------
__global__ __launch_bounds__(256, 4) void fused_kernel(
    const float* __restrict__ f, const short* __restrict__ Apack,
    const float* __restrict__ u2v, const float* __restrict__ v2v,
    const float* __restrict__ c0p, const float* __restrict__ flow,
    float* __restrict__ out)
{
    __shared__ unsigned short sH[HPX * SHS];
    __shared__ float sS[TH][TW][9];

    const int t    = threadIdx.x;
    const int lane = t & 63;
    const int w    = t >> 6;
    const int g    = lane >> 4, p = lane & 15;

    const int wg  = blockIdx.x;
    const int idx = (wg & 7) * 144 + (wg >> 3);
    const int b   = idx / 288;
    const int rem = idx - b * 288;
    const int ty  = rem / 12, tx = rem - ty * 12;
    const int y0  = ty * TH, x0 = tx * TW;
    const float* fb = f + (size_t)b * C_ * HW_;

#pragma unroll
    for (int it = 0; it < 7; ++it) {
        const int gi = it * 256 + t;
        if (gi < HPX * 16) {
            const int c8 = gi / HPX;
            const int px = gi - c8 * HPX;
            const int hy = px / HX;
            const int hx = px - hy * HX;
            const int gy = y0 + hy - 1, gx = x0 + hx - 1;
            bf16x8 v = {0, 0, 0, 0, 0, 0, 0, 0};
            if ((gy >= 0) && (gy < H_) && (gx >= 0) && (gx < W_)) {
                const float* src = fb + gy * W_ + gx;
#pragma unroll
                for (int j = 0; j < 8; ++j)
                    v[j] = (short)f2bf(src[(size_t)(c8 * 8 + j) * HW_]);
            }
            *(bf16x8*)(sH + px * SHS + c8 * 8) = v;
        }
    }
    __syncthreads();

    f32x4 acc[8];
#pragma unroll
    for (int rb = 0; rb < 8; ++rb) acc[rb] = (f32x4){0.f, 0.f, 0.f, 0.f};

#pragma unroll
    for (int ks = 0; ks < 4; ++ks) {
        const int hpx = (w + 1) * HX + (p + 1);
        const bf16x8 bfr = *(const bf16x8*)(sH + hpx * SHS + (ks * 4 + g) * 8);
#pragma unroll
        for (int rb = 0; rb < 8; ++rb) {
            const bf16x8 afr = *(const bf16x8*)(Apack +
                ((size_t)((rb * 4 + ks) * 64 + lane)) * 8);
            acc[rb] = __builtin_amdgcn_mfma_f32_16x16x32_bf16(afr, bfr, acc[rb], 0, 0, 0);
        }
    }

    const int L0 = ((lane & 16) << 1) | p;
    const int L1 = L0 + 16;
    uint2 pk[8];
#pragma unroll
    for (int rb = 0; rb < 8; ++rb) {
        const f32x4 uu = *(const f32x4*)(u2v + rb * 16 + g * 4);
        const f32x4 vv = acc[rb] + uu;
        pk[rb].x = (unsigned)f2bf(vv[0]) | ((unsigned)f2bf(vv[1]) << 16);
        pk[rb].y = (unsigned)f2bf(vv[2]) | ((unsigned)f2bf(vv[3]) << 16);
    }
    bf16x8 aS[4];
#pragma unroll
    for (int ks = 0; ks < 4; ++ks) {
        int dw[4];
#pragma unroll
        for (int dd = 0; dd < 4; ++dd) {
            const int v0 = (dd & 1) ? (int)pk[2 * ks].y     : (int)pk[2 * ks].x;
            const int v1 = (dd & 1) ? (int)pk[2 * ks + 1].y : (int)pk[2 * ks + 1].x;
            const int sl = (dd & 2) ? L1 : L0;
            const int w0 = __shfl(v0, sl, 64);
            const int w1 = __shfl(v1, sl, 64);
            dw[dd] = (g & 2) ? w1 : w0;
        }
        int4 qv = make_int4(dw[0], dw[1], dw[2], dw[3]);
        aS[ks] = *(bf16x8*)&qv;
    }

#pragma unroll
    for (int dy = 0; dy < 3; ++dy) {
        const int hyy = w + dy;
        f32x4 s0 = (f32x4){0.f, 0.f, 0.f, 0.f};
        f32x4 s1 = (f32x4){0.f, 0.f, 0.f, 0.f};
#pragma unroll
        for (int ks = 0; ks < 4; ++ks) {
            const int hpx0 = hyy * HX + p;
            const bf16x8 b0 = *(const bf16x8*)(sH + hpx0 * SHS + (ks * 4 + g) * 8);
            const bf16x8 b1 = *(const bf16x8*)(sH + (hpx0 + 2) * SHS + (ks * 4 + g) * 8);
            s0 = __builtin_amdgcn_mfma_f32_16x16x32_bf16(aS[ks], b0, s0, 0, 0, 0);
            s1 = __builtin_amdgcn_mfma_f32_16x16x32_bf16(aS[ks], b1, s1, 0, 0, 0);
        }
#pragma unroll
        for (int i = 0; i < 4; ++i) {
            const int x = g * 4 + i;
            const float val = (g < 2) ? s0[i] : s1[i];
            const int   d   = (g < 2) ? (p - x) : (x - p);
            const int   n9  = (g < 2) ? (dy * 3 + d) : (dy * 3 + 2 - d);
            if ((unsigned)d <= 2u) sS[w][x][n9] = val;
        }
    }

    const int r  = (lane >> 4) & 1;
    const int v  = lane >> 5;
    const int xl = lane & 15;
    const int gy = y0 + w, gx = x0 + xl;

    float beta = 0.f;
    const bool edge = (gx == 0) | (gx == W_ - 1) | (gy == 0) | (gy == H_ - 1);
    if (edge) {
        const int hpx = (w + 1) * HX + (xl + 1);
#pragma unroll
        for (int c8 = 0; c8 < 16; ++c8) {
            const uint4 hv = *(const uint4*)(sH + hpx * SHS + c8 * 8);
            const float4 va = *(const float4*)(v2v + c8 * 8);
            const float4 vb = *(const float4*)(v2v + c8 * 8 + 4);
            beta += bflo(hv.x) * va.x + bfhi(hv.x) * va.y
                  + bflo(hv.y) * va.z + bfhi(hv.y) * va.w
                  + bflo(hv.z) * vb.x + bfhi(hv.z) * vb.y
                  + bflo(hv.w) * vb.z + bfhi(hv.w) * vb.w;
        }
        beta += *c0p;
    }

    const float scale = 0.08838834764831845f;
    float sv[9], mk[9];
    int spn[9];
    float m = -1e30f;
#pragma unroll
    for (int n = 0; n < 9; ++n) {
        const int yn = gy + n / 3 - 1, xn = gx + n % 3 - 1;
        const bool ok = (yn >= 0) && (yn < H_) && (xn >= 0) && (xn < W_);
        mk[n]  = ok ? 1.f : 0.f;
        spn[n] = ok ? yn * W_ + xn : gy * W_ + gx;
        sv[n]  = ok ? (sS[w][xl][n] + beta) * scale : 0.f;
        m = fmaxf(m, sv[n]);
    }
    float e[9], sum = 0.f;
#pragma unroll
    for (int n = 0; n < 9; ++n) { e[n] = __expf(sv[n] - m); sum += e[n]; }
    const float inv = 1.f / sum;

    if (r == 0) {
        const float* f0 = flow + ((size_t)b * 2 + v) * HW_;
        float o = 0.f;
#pragma unroll
        for (int n = 0; n < 9; ++n) o += e[n] * mk[n] * f0[spn[n]];
        out[((size_t)b * 2 + v) * HW_ + gy * W_ + gx] = o * inv;
    }
}

// ===========================================================================
// DIAGNOSTIC PROBES — write only to d_ws scratch; repeated so they exceed the
// 40 us fill-kernel threshold and appear in rocprof top-5.
// ===========================================================================
#define REPS 16

// ---- probe 1: staging phase only, x16 ----
__global__ __launch_bounds__(256, 4) void probe_stage_kernel(
    const float* __restrict__ f, float* __restrict__ sink)
{
    __shared__ unsigned short sH[HPX * SHS];
    const int t   = threadIdx.x;
    const int wg  = blockIdx.x;
    const int idx = (wg & 7) * 144 + (wg >> 3);
    const int b   = idx / 288;
    const int rem = idx - b * 288;
    const int ty  = rem / 12, tx = rem - ty * 12;
    const int y0  = ty * TH, x0 = tx * TW;
    const float* fb = f + (size_t)b * C_ * HW_;

#pragma unroll 1
    for (int rep = 0; rep < REPS; ++rep) {
#pragma unroll
        for (int it = 0; it < 7; ++it) {
            const int gi = it * 256 + t;
            if (gi < HPX * 16) {
                const int c8 = gi / HPX;
                const int px = gi - c8 * HPX;
                const int hy = px / HX;
                const int hx = px - hy * HX;
                const int gy = y0 + hy - 1, gx = x0 + hx - 1;
                bf16x8 v = {0, 0, 0, 0, 0, 0, 0, 0};
                if ((gy >= 0) && (gy < H_) && (gx >= 0) && (gx < W_)) {
                    const float* src = fb + gy * W_ + gx;
#pragma unroll
                    for (int j = 0; j < 8; ++j)
                        v[j] = (short)f2bf(src[(size_t)(c8 * 8 + j) * HW_]);
                }
                *(bf16x8*)(sH + px * SHS + c8 * 8) = v;
            }
        }
        __syncthreads();
        asm volatile("" ::: "memory");
    }
    sink[(size_t)wg * 256 + t] = (float)sH[t] + (float)sH[t + 4096];
}

// ---- probe 2: stage once, then compute phase x16 (value-perturbed) ----
__global__ __launch_bounds__(256, 4) void probe_compute_kernel(
    const float* __restrict__ f, const short* __restrict__ Apack,
    const float* __restrict__ u2v, const float* __restrict__ v2v,
    const float* __restrict__ c0p, const float* __restrict__ flow,
    float* __restrict__ sink)
{
    __shared__ unsigned short sH[HPX * SHS];
    __shared__ float sS[TH][TW][9];

    const int t    = threadIdx.x;
    const int lane = t & 63;
    const int w    = t >> 6;
    const int g    = lane >> 4, p = lane & 15;

    const int wg  = blockIdx.x;
    const int idx = (wg & 7) * 144 + (wg >> 3);
    const int b   = idx / 288;
    const int rem = idx - b * 288;
    const int ty  = rem / 12, tx = rem - ty * 12;
    const int y0  = ty * TH, x0 = tx * TW;
    const float* fb = f + (size_t)b * C_ * HW_;

#pragma unroll
    for (int it = 0; it < 7; ++it) {
        const int gi = it * 256 + t;
        if (gi < HPX * 16) {
            const int c8 = gi / HPX;
            const int px = gi - c8 * HPX;
            const int hy = px / HX;
            const int hx = px - hy * HX;
            const int gy = y0 + hy - 1, gx = x0 + hx - 1;
            bf16x8 v = {0, 0, 0, 0, 0, 0, 0, 0};
            if ((gy >= 0) && (gy < H_) && (gx >= 0) && (gx < W_)) {
                const float* src = fb + gy * W_ + gx;
#pragma unroll
                for (int j = 0; j < 8; ++j)
                    v[j] = (short)f2bf(src[(size_t)(c8 * 8 + j) * HW_]);
            }
            *(bf16x8*)(sH + px * SHS + c8 * 8) = v;
        }
    }
    __syncthreads();

    float osink = 0.f;
#pragma unroll 1
    for (int rep = 0; rep < REPS; ++rep) {
        asm volatile("" ::: "memory");
        const float pert = (float)rep * 1e-30f;   // defeats MFMA value-CSE

        f32x4 acc[8];
#pragma unroll
        for (int rb = 0; rb < 8; ++rb) acc[rb] = (f32x4){pert, 0.f, 0.f, 0.f};

#pragma unroll
        for (int ks = 0; ks < 4; ++ks) {
            const int hpx = (w + 1) * HX + (p + 1);
            const bf16x8 bfr = *(const bf16x8*)(sH + hpx * SHS + (ks * 4 + g) * 8);
#pragma unroll
            for (int rb = 0; rb < 8; ++rb) {
                const bf16x8 afr = *(const bf16x8*)(Apack +
                    ((size_t)((rb * 4 + ks) * 64 + lane)) * 8);
                acc[rb] = __builtin_amdgcn_mfma_f32_16x16x32_bf16(afr, bfr, acc[rb], 0, 0, 0);
            }
        }

        const int L0 = ((lane & 16) << 1) | p;
        const int L1 = L0 + 16;
        uint2 pk[8];
#pragma unroll
        for (int rb = 0; rb < 8; ++rb) {
            const f32x4 uu = *(const f32x4*)(u2v + rb * 16 + g * 4);
            const f32x4 vv = acc[rb] + uu;
            pk[rb].x = (unsigned)f2bf(vv[0]) | ((unsigned)f2bf(vv[1]) << 16);
            pk[rb].y = (unsigned)f2bf(vv[2]) | ((unsigned)f2bf(vv[3]) << 16);
        }
        bf16x8 aS[4];
#pragma unroll
        for (int ks = 0; ks < 4; ++ks) {
            int dw[4];
#pragma unroll
            for (int dd = 0; dd < 4; ++dd) {
                const int v0 = (dd & 1) ? (int)pk[2 * ks].y     : (int)pk[2 * ks].x;
                const int v1 = (dd & 1) ? (int)pk[2 * ks + 1].y : (int)pk[2 * ks + 1].x;
                const int sl = (dd & 2) ? L1 : L0;
                const int w0 = __shfl(v0, sl, 64);
                const int w1 = __shfl(v1, sl, 64);
                dw[dd] = (g & 2) ? w1 : w0;
            }
            int4 qv = make_int4(dw[0], dw[1], dw[2], dw[3]);
            aS[ks] = *(bf16x8*)&qv;
        }

#pragma unroll
        for (int dy = 0; dy < 3; ++dy) {
            const int hyy = w + dy;
            f32x4 s0 = (f32x4){0.f, 0.f, 0.f, 0.f};
            f32x4 s1 = (f32x4){0.f, 0.f, 0.f, 0.f};
#pragma unroll
            for (int ks = 0; ks < 4; ++ks) {
                const int hpx0 = hyy * HX + p;
                const bf16x8 b0 = *(const bf16x8*)(sH + hpx0 * SHS + (ks * 4 + g) * 8);
                const bf16x8 b1 = *(const bf16x8*)(sH + (hpx0 + 2) * SHS + (ks * 4 + g) * 8);
                s0 = __builtin_amdgcn_mfma_f32_16x16x32_bf16(aS[ks], b0, s0, 0, 0, 0);
                s1 = __builtin_amdgcn_mfma_f32_16x16x32_bf16(aS[ks], b1, s1, 0, 0, 0);
            }
#pragma unroll
            for (int i = 0; i < 4; ++i) {
                const int x = g * 4 + i;
                const float val = (g < 2) ? s0[i] : s1[i];
                const int   d   = (g < 2) ? (p - x) : (x - p);
                const int   n9  = (g < 2) ? (dy * 3 + d) : (dy * 3 + 2 - d);
                if ((unsigned)d <= 2u) sS[w][x][n9] = val;
            }
        }

        const int v  = lane >> 5;
        const int xl = lane & 15;
        const int gy = y0 + w, gx = x0 + xl;

        float beta = 0.f;
        const bool edge = (gx == 0) | (gx == W_ - 1) | (gy == 0) | (gy == H_ - 1);
        if (edge) {
            const int hpx = (w + 1) * HX + (xl + 1);
#pragma unroll
            for (int c8 = 0; c8 < 16; ++c8) {
                const uint4 hv = *(const uint4*)(sH + hpx * SHS + c8 * 8);
                const float4 va = *(const float4*)(v2v + c8 * 8);
                const float4 vb = *(const float4*)(v2v + c8 * 8 + 4);
                beta += bflo(hv.x) * va.x + bfhi(hv.x) * va.y
                      + bflo(hv.y) * va.z + bfhi(hv.y) * va.w
                      + bflo(hv.z) * vb.x + bfhi(hv.z) * vb.y
                      + bflo(hv.w) * vb.z + bfhi(hv.w) * vb.w;
            }
            beta += *c0p;
        }

        const float scale = 0.08838834764831845f;
        float sv[9], mk[9];
        int spn[9];
        float m = -1e30f;
#pragma unroll
        for (int n = 0; n < 9; ++n) {
            const int yn = gy + n / 3 - 1, xn = gx + n % 3 - 1;
            const bool ok = (yn >= 0) && (yn < H_) && (xn >= 0) && (xn < W_);
            mk[n]  = ok ? 1.f : 0.f;
            spn[n] = ok ? yn * W_ + xn : gy * W_ + gx;
            sv[n]  = ok ? (sS[w][xl][n] + beta) * scale : 0.f;
            m = fmaxf(m, sv[n]);
        }
        float e[9], sum = 0.f;
#pragma unroll
        for (int n = 0; n < 9; ++n) { e[n] = __expf(sv[n] - m); sum += e[n]; }
        const float inv = 1.f / sum;

        const float* f0 = flow + ((size_t)b * 2 + v) * HW_;
        float o = 0.f;
#pragma unroll
        for (int n = 0; n < 9; ++n) o += e[n] * mk[n] * f0[spn[n]];
        osink += o * inv;
    }
    sink[(size_t)wg * 256 + t] = osink;
}

// ---- probe 3: perfectly-coalesced stream: read f fp32, write bf16 planar ----
__global__ __launch_bounds__(256, 8) void probe_cpy_kernel(
    const float* __restrict__ f, unsigned short* __restrict__ dst)
{
    const size_t tid = (size_t)blockIdx.x * 256 + threadIdx.x;   // grid 2304
#pragma unroll 1
    for (int rep = 0; rep < 8; ++rep) {
#pragma unroll 1
        for (int i = 0; i < 4; ++i) {
            const size_t e4 = tid + (size_t)i * 2304 * 256;      // 2359296 float4 total
            const float4 v = *(const float4*)(f + e4 * 4);
            uint2 o;
            o.x = (unsigned)f2bf(v.x) | ((unsigned)f2bf(v.y) << 16);
            o.y = (unsigned)f2bf(v.z) | ((unsigned)f2bf(v.w) << 16);
            *(uint2*)(dst + e4 * 4) = o;
        }
        asm volatile("" ::: "memory");
    }
}

extern "C" void kernel_launch(void* const* d_in, const int* in_sizes, int n_in,
                              void* d_out, int out_size, void* d_ws, size_t ws_size,
                              hipStream_t stream) {
    const float* f   = (const float*)d_in[0];
    const float* flw = (const float*)d_in[1];
    const float* Wq  = (const float*)d_in[2];
    const float* bq  = (const float*)d_in[3];
    const float* Wk  = (const float*)d_in[4];
    const float* bk  = (const float*)d_in[5];
    float* out = (float*)d_out;

    short* Apack = (short*)d_ws;                  // 32 KB
    float* u2    = (float*)(Apack + 128 * 128);   // 512 B
    float* v2    = u2 + 128;                      // 512 B
    float* c0    = v2 + 128;                      // 4 B

    prep_kernel<<<9, 256, 0, stream>>>(Wq, Wk, bq, bk, Apack, u2, v2, c0);
    fused_kernel<<<1152, 256, 0, stream>>>(f, Apack, u2, v2, c0, flw, out);

    // diagnostic probes (scratch-only writes; skipped if workspace too small)
    if (ws_size >= (64u << 20)) {
        float* sinkA = (float*)((char*)d_ws + (1u << 20));
        float* sinkB = (float*)((char*)d_ws + (4u << 20));
        unsigned short* cpyD = (unsigned short*)((char*)d_ws + (8u << 20));
        probe_stage_kernel<<<1152, 256, 0, stream>>>(f, sinkA);
        probe_compute_kernel<<<1152, 256, 0, stream>>>(f, Apack, u2, v2, c0, flw, sinkB);
        probe_cpy_kernel<<<2304, 256, 0, stream>>>(f, cpyD);
    }
}

// Round 10
// 48.842 us; speedup vs baseline: 8.9292x; 8.9292x over previous
//
#include <hip/hip_runtime.h>
#include <hip/hip_bf16.h>
#include <math.h>

#define B_   4
#define C_   128
#define H_   96
#define W_   192
#define HW_  (H_*W_)

typedef __attribute__((ext_vector_type(8))) short bf16x8;
typedef __attribute__((ext_vector_type(4))) float f32x4;

__device__ __forceinline__ unsigned f2bfu(float f) {
    __hip_bfloat16 h = __float2bfloat16(f);     // pairs fuse to v_cvt_pk_bf16_f32
    return (unsigned)*(unsigned short*)&h;
}
__device__ __forceinline__ float bflo(unsigned u) { return __uint_as_float(u << 16); }
__device__ __forceinline__ float bfhi(unsigned u) { return __uint_as_float(u & 0xFFFF0000u); }

__device__ __forceinline__ bf16x8 pack8(const float* v) {
    int4 q;
    q.x = (int)(f2bfu(v[0]) | (f2bfu(v[1]) << 16));
    q.y = (int)(f2bfu(v[2]) | (f2bfu(v[3]) << 16));
    q.z = (int)(f2bfu(v[4]) | (f2bfu(v[5]) << 16));
    q.w = (int)(f2bfu(v[6]) | (f2bfu(v[7]) << 16));
    return *(bf16x8*)&q;
}

// ---------------------------------------------------------------------------
// prep: blocks 0..7 compute Mc = Wk^T Wq rows rb*16..+15, written directly in
// bf16 MFMA A-fragment order. block 8: u2 = Wk^T bq, v2 = Wq^T bk, c0 = bq.bk
// c-loop: 8-wide batches -> 24 independent loads in flight.
// ---------------------------------------------------------------------------
__global__ __launch_bounds__(256) void prep_kernel(
    const float* __restrict__ Wq, const float* __restrict__ Wk,
    const float* __restrict__ bq, const float* __restrict__ bk,
    short* __restrict__ Apack, float* __restrict__ u2,
    float* __restrict__ v2, float* __restrict__ c0)
{
    if (blockIdx.x < 8) {
        const int rb   = blockIdx.x;
        const int t    = threadIdx.x;
        const int lane = t & 63;
        const int row  = rb * 16 + (lane & 15);
        const int colb = (t >> 6) * 32 + (lane >> 4) * 8;
        float a[8];
#pragma unroll
        for (int j = 0; j < 8; ++j) a[j] = 0.f;
#pragma unroll 1
        for (int c = 0; c < C_; c += 8) {
            float  wk[8];
            float4 w0[8], w1[8];
#pragma unroll
            for (int u = 0; u < 8; ++u) {
                wk[u] = Wk[(c + u) * C_ + row];
                w0[u] = *(const float4*)(Wq + (c + u) * C_ + colb);
                w1[u] = *(const float4*)(Wq + (c + u) * C_ + colb + 4);
            }
#pragma unroll
            for (int u = 0; u < 8; ++u) {
                a[0] = fmaf(wk[u], w0[u].x, a[0]); a[1] = fmaf(wk[u], w0[u].y, a[1]);
                a[2] = fmaf(wk[u], w0[u].z, a[2]); a[3] = fmaf(wk[u], w0[u].w, a[3]);
                a[4] = fmaf(wk[u], w1[u].x, a[4]); a[5] = fmaf(wk[u], w1[u].y, a[5]);
                a[6] = fmaf(wk[u], w1[u].z, a[6]); a[7] = fmaf(wk[u], w1[u].w, a[7]);
            }
        }
        bf16x8 v = pack8(a);
        *(bf16x8*)(Apack + ((size_t)rb * 256 + t) * 8) = v;
    } else {
        const int t = threadIdx.x;
        if (t < 128) {
            float a = 0.f;
            for (int c = 0; c < C_; ++c) a = fmaf(Wk[c * C_ + t], bq[c], a);
            u2[t] = a;
        } else {
            const int i = t - 128;
            float a = 0.f;
            for (int c = 0; c < C_; ++c) a = fmaf(Wq[c * C_ + i], bk[c], a);
            v2[i] = a;
        }
        if (t == 0) {
            float a = 0.f;
            for (int c = 0; c < C_; ++c) a = fmaf(bq[c], bk[c], a);
            c0[0] = a;
        }
    }
}

// ---------------------------------------------------------------------------
// fused, wave-autonomous: wave = 1 output row x 14 px (window = 16 px incl.
// L/R halo, loaded straight from global; clamped addrs, OOB masked later).
// R = Mc f via MFMA (B-frags from global) -> in-reg repack -> S via 3 MFMA
// chains (one un-shifted B-frag per dy gives all 3 dx diagonals for output
// rows 1..14) -> band extract to 2.3KB LDS -> per-lane softmax + beta + PV.
// No __syncthreads, no halo LDS. Block = 4 waves = 4 consecutive rows.
// Occupancy: VGPR-capped (~16 waves/CU), LDS no longer binding (64KB rule).
// ---------------------------------------------------------------------------
__global__ __launch_bounds__(256, 4) void fused_kernel(
    const float* __restrict__ f, const short* __restrict__ Apack,
    const float* __restrict__ u2v, const float* __restrict__ v2v,
    const float* __restrict__ c0p, const float* __restrict__ flow,
    float* __restrict__ out)
{
    __shared__ float sS[4][16][9];              // 2304 B, per-wave private

    const int t    = threadIdx.x;
    const int lane = t & 63;
    const int w    = t >> 6;
    const int g    = lane >> 4, p = lane & 15;

    const int wg  = blockIdx.x;                 // 1344 = 8*168
    const int idx = (wg & 7) * 168 + (wg >> 3); // XCD-band swizzle (bijective)
    const int b   = idx / 336;
    const int rem = idx - b * 336;
    const int ty  = rem / 14, tx = rem - ty * 14;
    const int y   = ty * 4 + w;                 // 0..95
    int x0 = tx * 14; if (x0 > W_ - 14) x0 = W_ - 14;
    const float* fb = f + (size_t)b * C_ * HW_;

    const int xw = x0 - 1 + p;                            // window column
    const int xc = xw < 0 ? 0 : (xw > W_ - 1 ? W_ - 1 : xw);  // clamped (masked later)

    // ---- center-row f fragments (kept for S dy=1 and beta) ----
    bf16x8 fC[4];
#pragma unroll
    for (int ks = 0; ks < 4; ++ks) {
        const float* src = fb + (size_t)(ks * 32 + g * 8) * HW_ + y * W_ + xc;
        float v[8];
#pragma unroll
        for (int j = 0; j < 8; ++j) v[j] = src[(size_t)j * HW_];
        fC[ks] = pack8(v);
    }

    // ---- R-GEMM: r[128 ch][16 window px] ----
    f32x4 acc[8];
#pragma unroll
    for (int rb = 0; rb < 8; ++rb) acc[rb] = (f32x4){0.f, 0.f, 0.f, 0.f};
#pragma unroll
    for (int ks = 0; ks < 4; ++ks) {
#pragma unroll
        for (int rb = 0; rb < 8; ++rb) {
            const bf16x8 afr = *(const bf16x8*)(Apack +
                ((size_t)((rb * 4 + ks) * 64 + lane)) * 8);
            acc[rb] = __builtin_amdgcn_mfma_f32_16x16x32_bf16(afr, fC[ks], acc[rb], 0, 0, 0);
        }
    }

    // ---- in-register repack C-frag -> A-frag (validated mapping) ----
    const int L0 = ((lane & 16) << 1) | p;
    const int L1 = L0 + 16;
    uint2 pk[8];
#pragma unroll
    for (int rb = 0; rb < 8; ++rb) {
        const f32x4 uu = *(const f32x4*)(u2v + rb * 16 + g * 4);
        const f32x4 vv = acc[rb] + uu;
        pk[rb].x = f2bfu(vv[0]) | (f2bfu(vv[1]) << 16);
        pk[rb].y = f2bfu(vv[2]) | (f2bfu(vv[3]) << 16);
    }
    bf16x8 aS[4];
#pragma unroll
    for (int ks = 0; ks < 4; ++ks) {
        int dw[4];
#pragma unroll
        for (int dd = 0; dd < 4; ++dd) {
            const int v0 = (dd & 1) ? (int)pk[2 * ks].y     : (int)pk[2 * ks].x;
            const int v1 = (dd & 1) ? (int)pk[2 * ks + 1].y : (int)pk[2 * ks + 1].x;
            const int sl = (dd & 2) ? L1 : L0;
            const int w0 = __shfl(v0, sl, 64);
            const int w1 = __shfl(v1, sl, 64);
            dw[dd] = (g & 2) ? w1 : w0;
        }
        int4 qv = make_int4(dw[0], dw[1], dw[2], dw[3]);
        aS[ks] = *(bf16x8*)&qv;
    }

    // ---- S-GEMM: one B-frag per dy; D[row][col] = r(win[row]).f(win[col]);
    //      band n = 3*dy + (p - row + 1) for |p-row|<=1, rows 1..14 valid ----
#pragma unroll
    for (int dy = 0; dy < 3; ++dy) {
        bf16x8 fN[4];
        if (dy == 1) {
#pragma unroll
            for (int ks = 0; ks < 4; ++ks) fN[ks] = fC[ks];
        } else {
            int yy = y + dy - 1;
            yy = yy < 0 ? 0 : (yy > H_ - 1 ? H_ - 1 : yy);   // clamped (masked later)
#pragma unroll
            for (int ks = 0; ks < 4; ++ks) {
                const float* src = fb + (size_t)(ks * 32 + g * 8) * HW_ + yy * W_ + xc;
                float v[8];
#pragma unroll
                for (int j = 0; j < 8; ++j) v[j] = src[(size_t)j * HW_];
                fN[ks] = pack8(v);
            }
        }
        f32x4 sd = (f32x4){0.f, 0.f, 0.f, 0.f};
#pragma unroll
        for (int ks = 0; ks < 4; ++ks)
            sd = __builtin_amdgcn_mfma_f32_16x16x32_bf16(aS[ks], fN[ks], sd, 0, 0, 0);
#pragma unroll
        for (int i = 0; i < 4; ++i) {
            const int row = g * 4 + i;
            const int d1  = p - row + 1;
            if ((unsigned)d1 <= 2u) sS[w][row][dy * 3 + d1] = sd[i];
        }
    }
    // no barrier: sS[w] produced and consumed by the same wave

    // ---- beta = v2.f_p + c0 (exact softmax shift; matters only at edges) ----
    float bl = 0.f;
#pragma unroll
    for (int ks = 0; ks < 4; ++ks) {
        const f32x4 va = *(const f32x4*)(v2v + ks * 32 + g * 8);
        const f32x4 vb = *(const f32x4*)(v2v + ks * 32 + g * 8 + 4);
        const int4 qd = *(const int4*)&fC[ks];
        bl += bflo((unsigned)qd.x) * va[0] + bfhi((unsigned)qd.x) * va[1]
            + bflo((unsigned)qd.y) * va[2] + bfhi((unsigned)qd.y) * va[3]
            + bflo((unsigned)qd.z) * vb[0] + bfhi((unsigned)qd.z) * vb[1]
            + bflo((unsigned)qd.w) * vb[2] + bfhi((unsigned)qd.w) * vb[3];
    }
    bl += __shfl_xor(bl, 16, 64);
    bl += __shfl_xor(bl, 32, 64);                // sum over g-groups -> beta(px win[p])
    const float beta = bl + *c0p;

    // ---- softmax + flow PV: lane rr=p serves output px x0-1+rr (rr 1..14),
    //      v = g>>1, one writer per (px,v) via (g&1)==0 ----
    const int rr = p;
    const int vch = g >> 1;
    const int gy = y, gx = x0 - 1 + rr;

    const float scale = 0.08838834764831845f;    // 1/sqrt(128)
    float sv[9], mk[9];
    int spn[9];
    float m = -1e30f;
#pragma unroll
    for (int n = 0; n < 9; ++n) {
        const int yn = gy + n / 3 - 1, xn = gx + n % 3 - 1;
        const bool ok = (yn >= 0) && (yn < H_) && (xn >= 0) && (xn < W_);
        mk[n]  = ok ? 1.f : 0.f;
        spn[n] = ok ? yn * W_ + xn : 0;
        sv[n]  = ok ? (sS[w][rr][n] + beta) * scale : 0.f;
        m = fmaxf(m, sv[n]);
    }
    float e[9], sum = 0.f;
#pragma unroll
    for (int n = 0; n < 9; ++n) { e[n] = __expf(sv[n] - m); sum += e[n]; }
    const float inv = 1.f / sum;

    if (((g & 1) == 0) && (rr >= 1) && (rr <= 14)) {
        const float* f0 = flow + ((size_t)b * 2 + vch) * HW_;
        float o = 0.f;
#pragma unroll
        for (int n = 0; n < 9; ++n) o += e[n] * mk[n] * f0[spn[n]];
        out[((size_t)b * 2 + vch) * HW_ + gy * W_ + gx] = o * inv;
    }
}

extern "C" void kernel_launch(void* const* d_in, const int* in_sizes, int n_in,
                              void* d_out, int out_size, void* d_ws, size_t ws_size,
                              hipStream_t stream) {
    const float* f   = (const float*)d_in[0];
    const float* flw = (const float*)d_in[1];
    const float* Wq  = (const float*)d_in[2];
    const float* bq  = (const float*)d_in[3];
    const float* Wk  = (const float*)d_in[4];
    const float* bk  = (const float*)d_in[5];
    float* out = (float*)d_out;

    short* Apack = (short*)d_ws;                  // 32 KB
    float* u2    = (float*)(Apack + 128 * 128);   // 512 B
    float* v2    = u2 + 128;                      // 512 B
    float* c0    = v2 + 128;                      // 4 B

    prep_kernel<<<9, 256, 0, stream>>>(Wq, Wk, bq, bk, Apack, u2, v2, c0);
    fused_kernel<<<1344, 256, 0, stream>>>(f, Apack, u2, v2, c0, flw, out);
}